// Round 11
// baseline (28.317 us; speedup 1.0000x reference)
//
#include <hip/hip_runtime.h>
#include <math.h>

// FBPINN: out(x) = sum_k w_k(x)*subnet_k(x) / sum_k w_k(x), x scalar in [0,1].
// Two dispatches:
//  1) build_tables: numerator table sum_k w_k*o_k at TBL grid points.
//     Block = 256 thr (4 waves) per 64-pt stretch; wave = subnet slot
//     klo_b+slot (wave-uniform). WEIGHT DELIVERY = REGISTERS + v_readlane:
//     each lane stages 36 floats (9 coalesced float4 loads, one round-trip);
//     the MLP is fully unrolled with compile-time readlane(reg, lane) that
//     broadcasts each weight to an SGPR consumed directly by v_fma. This
//     replaces the ~540-deep ds_read->FMA latency chain (R8: ~13.7us build,
//     invariant to occupancy/T per R9 falsification) with pure VALU work
//     (~10K cyc/wave ~ 4.3us at 1 wave/SIMD). No LDS for weights.
//  2) eval_lerp: float4 lerp of the flat table; denominator ANALYTIC
//     (<=4 cosine windows of x only). Kernel-boundary coherence.
// Lerp error ~2.5e-6 at TBL=16384 << 7.3e-3 threshold (bf16 floor 1.95e-3).

#define KSUB 16
#define NW 32
#define TBL 16384
#define SLOTS 4   // active-k union over a 64-pt stretch: <=4 ints from klo_b

// tanh(x) = 1 - 2/(exp(2x)+1); v_exp_f32 is exp2 -> scale by 2*log2(e).
static __device__ __forceinline__ float fast_tanh(float v) {
    float e = __builtin_amdgcn_exp2f(v * 2.8853900817779268f);
    return 1.0f - 2.0f * __builtin_amdgcn_rcpf(e + 1.0f);
}

// cos(pi*u), u in [0,1]: v_cos_f32 takes revolutions.
static __device__ __forceinline__ float cos_pi(float u) {
    return __builtin_amdgcn_cosf(0.5f * u);
}

static __device__ __forceinline__ float window_w(float x, int k) {
    const float invTW = 20.0f;  // 1/0.05
    float xmin = (float)k * 0.0625f - 0.06f;
    float xmax = (float)(k + 1) * 0.0625f + 0.06f;
    float up = (x - xmin + 0.025f) * invTW;
    float dn = (xmax + 0.025f - x) * invTW;
    up = fminf(fmaxf(up, 0.0f), 1.0f);
    dn = fminf(fmaxf(dn, 0.0f), 1.0f);
    return 0.25f * (1.0f - cos_pi(up)) * (1.0f - cos_pi(dn));
}

// Active subnets at x: k in (16x-2.36, 16x+1.36) => at most 4, klo..klo+3.
static __device__ __forceinline__ float den_analytic(float xv) {
    int klo = (int)ceilf(16.0f * xv - 2.36f);
    float den = 0.f;
#pragma unroll
    for (int j = 0; j < 4; ++j) {
        int k = klo + j;
        if (k >= 0 && k < KSUB) den += window_w(xv, k);
    }
    return den;
}

// readlane broadcast: weight bits from (reg, lane) -> SGPR, used as the
// scalar operand of v_fma. All indices compile-time under full unroll.
#define RLF(r, ln) __uint_as_float(__builtin_amdgcn_readlane(__float_as_uint(r), (ln)))
// W1 flat f = o*32+j lives in tw[(f>>8)*4 + (f&3)] of lane (f&255)>>2.
#define W1E(o, j) RLF(tw[((((o)*32+(j)) >> 8) * 4) + (((o)*32+(j)) & 3)], ((((o)*32+(j)) & 255) >> 2))
#define W2E(o, j) RLF(tw[16 + ((((o)*32+(j)) >> 8) * 4) + (((o)*32+(j)) & 3)], ((((o)*32+(j)) & 255) >> 2))
// tail flat ft (0..159): W0|B0|B1|B2|W3 in 32-float chunks; lane = (ft>>5)*8
// + ((ft&31)>>2), reg tw[32 + (ft&3)].
#define TAILE(ft) RLF(tw[32 + ((ft) & 3)], (((ft) >> 5) * 8) + ((((ft) & 31)) >> 2))
#define W0E(o) TAILE(o)
#define B0E(o) TAILE(32 + (o))
#define B1E(o) TAILE(64 + (o))
#define B2E(o) TAILE(96 + (o))
#define W3E(j) TAILE(128 + (j))

// grid = TBL/64 blocks x 256 threads (4 slot-waves). See header.
__global__ __launch_bounds__(256) void build_tables(
    const float* __restrict__ W0, const float* __restrict__ B0,
    const float* __restrict__ W1, const float* __restrict__ B1,
    const float* __restrict__ W2, const float* __restrict__ B2,
    const float* __restrict__ W3, const float* __restrict__ B3,
    float* __restrict__ gnum)
{
    __shared__ float part[SLOTS][64];

    const int lane = threadIdx.x & 63;
    const int slot = threadIdx.x >> 6;       // wave id = subnet slot
    const int str  = blockIdx.x;
    const int i    = str * 64 + lane;
    const float inv = 1.0f / (float)(TBL - 1);
    const float xg  = (float)i * inv;

    float x_lo = (float)(str * 64) * inv;
    int klo_b = (int)ceilf(16.0f * x_lo - 2.36f);
    const int k  = klo_b + slot;             // wave-uniform
    const int kc = min(max(k, 0), KSUB - 1);

    // ---- stage this wave's 8.7KB weight set into 36 VGPRs/lane ----
    float tw[36];
    {
        const float4* gW1 = reinterpret_cast<const float4*>(&W1[kc * NW * NW]);
        const float4* gW2 = reinterpret_cast<const float4*>(&W2[kc * NW * NW]);
#pragma unroll
        for (int c = 0; c < 4; ++c) {
            float4 v = gW1[c * 64 + lane];
            tw[c * 4 + 0] = v.x; tw[c * 4 + 1] = v.y;
            tw[c * 4 + 2] = v.z; tw[c * 4 + 3] = v.w;
        }
#pragma unroll
        for (int c = 0; c < 4; ++c) {
            float4 v = gW2[c * 64 + lane];
            tw[16 + c * 4 + 0] = v.x; tw[16 + c * 4 + 1] = v.y;
            tw[16 + c * 4 + 2] = v.z; tw[16 + c * 4 + 3] = v.w;
        }
        const int a = lane >> 3;             // 0..7 (0..4 carry data)
        const int e = (lane & 7) * 4;
        const float* sp = (a == 0) ? &W0[kc * NW] :
                          (a == 1) ? &B0[kc * NW] :
                          (a == 2) ? &B1[kc * NW] :
                          (a == 3) ? &B2[kc * NW] : &W3[kc * NW];
        float4 v = make_float4(0.f, 0.f, 0.f, 0.f);
        if (a < 5) v = *reinterpret_cast<const float4*>(&sp[e]);
        tw[32] = v.x; tw[33] = v.y; tw[34] = v.z; tw[35] = v.w;
    }

    // ---- evaluate subnet kc at this lane's point, weights via readlane ----
    const float INVS = 10.958904109589041f;  // 1/0.09125 (uniform scale)
    float xn = (xg - ((float)kc + 0.5f) * 0.0625f) * INVS;

    float h0[NW], h1[NW];
#pragma unroll
    for (int o = 0; o < NW; ++o)
        h0[o] = fast_tanh(fmaf(W0E(o), xn, B0E(o)));
#pragma unroll
    for (int o = 0; o < NW; ++o) {
        float a0 = B1E(o), a1 = 0.f, a2 = 0.f, a3 = 0.f;
#pragma unroll
        for (int j = 0; j < NW; j += 4) {
            a0 = fmaf(W1E(o, j + 0), h0[j + 0], a0);
            a1 = fmaf(W1E(o, j + 1), h0[j + 1], a1);
            a2 = fmaf(W1E(o, j + 2), h0[j + 2], a2);
            a3 = fmaf(W1E(o, j + 3), h0[j + 3], a3);
        }
        h1[o] = fast_tanh((a0 + a1) + (a2 + a3));
    }
#pragma unroll
    for (int o = 0; o < NW; ++o) {
        float a0 = B2E(o), a1 = 0.f, a2 = 0.f, a3 = 0.f;
#pragma unroll
        for (int j = 0; j < NW; j += 4) {
            a0 = fmaf(W2E(o, j + 0), h1[j + 0], a0);
            a1 = fmaf(W2E(o, j + 1), h1[j + 1], a1);
            a2 = fmaf(W2E(o, j + 2), h1[j + 2], a2);
            a3 = fmaf(W2E(o, j + 3), h1[j + 3], a3);
        }
        h0[o] = fast_tanh((a0 + a1) + (a2 + a3));  // reuse h0 as h2
    }
    float a0 = B3[kc], a1 = 0.f, a2 = 0.f, a3 = 0.f;
#pragma unroll
    for (int j = 0; j < NW; j += 4) {
        a0 = fmaf(W3E(j + 0), h0[j + 0], a0);
        a1 = fmaf(W3E(j + 1), h0[j + 1], a1);
        a2 = fmaf(W3E(j + 2), h0[j + 2], a2);
        a3 = fmaf(W3E(j + 3), h0[j + 3], a3);
    }
    float out_o = (a0 + a1) + (a2 + a3);

    float wgt = window_w(xg, kc);
    part[slot][lane] = (k >= 0 && k < KSUB) ? wgt * out_o : 0.0f;
    __syncthreads();
    if (threadIdx.x < 64) {
        gnum[i] = (part[0][lane] + part[1][lane]) +
                  (part[2][lane] + part[3][lane]);
    }
}

// Lerp the numerator table; denominator computed analytically per point.
__global__ void eval_lerp(const float* __restrict__ x,
                          const float* __restrict__ gnum,
                          float* __restrict__ out, int N)
{
    const float scaleT = (float)(TBL - 1);
    int idx = blockIdx.x * blockDim.x + threadIdx.x;
    int base = idx * 4;
    if (base + 3 < N) {
        float4 xv = *reinterpret_cast<const float4*>(&x[base]);
        float4 r;
        float* rp = &r.x;
        const float* xp = &xv.x;
#pragma unroll
        for (int j = 0; j < 4; ++j) {
            float xj = xp[j];
            float t = fminf(fmaxf(xj * scaleT, 0.0f), scaleT);
            int i0 = (int)t;
            if (i0 > TBL - 2) i0 = TBL - 2;
            float f = t - (float)i0;
            float n0 = gnum[i0], n1 = gnum[i0 + 1];
            float num = fmaf(f, n1 - n0, n0);
            float den = den_analytic(xj);
            rp[j] = num * __builtin_amdgcn_rcpf(den + 1e-12f);
        }
        *reinterpret_cast<float4*>(&out[base]) = r;
    } else {
        for (int j = base; j < N; ++j) {
            float xj = x[j];
            float t = fminf(fmaxf(xj * scaleT, 0.0f), scaleT);
            int i0 = (int)t;
            if (i0 > TBL - 2) i0 = TBL - 2;
            float f = t - (float)i0;
            float num = fmaf(f, gnum[i0 + 1] - gnum[i0], gnum[i0]);
            float den = den_analytic(xj);
            out[j] = num * __builtin_amdgcn_rcpf(den + 1e-12f);
        }
    }
}

// ---- fallback path (tiny ws only): direct evaluation via global loads ----
static __device__ __forceinline__ float subnet_eval_g(
    float xn, int kc,
    const float* __restrict__ W0, const float* __restrict__ B0,
    const float* __restrict__ W1, const float* __restrict__ B1,
    const float* __restrict__ W2, const float* __restrict__ B2,
    const float* __restrict__ W3, const float* __restrict__ B3)
{
    float h0[NW], h1[NW];
#pragma unroll
    for (int o = 0; o < NW; ++o)
        h0[o] = fast_tanh(fmaf(W0[kc * NW + o], xn, B0[kc * NW + o]));
#pragma unroll
    for (int o = 0; o < NW; ++o) {
        float a = B1[kc * NW + o];
        const float* row = &W1[kc * NW * NW + o * NW];
#pragma unroll
        for (int j = 0; j < NW; ++j) a = fmaf(row[j], h0[j], a);
        h1[o] = fast_tanh(a);
    }
#pragma unroll
    for (int o = 0; o < NW; ++o) {
        float a = B2[kc * NW + o];
        const float* row = &W2[kc * NW * NW + o * NW];
#pragma unroll
        for (int j = 0; j < NW; ++j) a = fmaf(row[j], h1[j], a);
        h0[o] = fast_tanh(a);
    }
    float a = B3[kc];
#pragma unroll
    for (int j = 0; j < NW; ++j) a = fmaf(W3[kc * NW + j], h0[j], a);
    return a;
}

__global__ void direct_eval(
    const float* __restrict__ x,
    const float* __restrict__ W0, const float* __restrict__ B0,
    const float* __restrict__ W1, const float* __restrict__ B1,
    const float* __restrict__ W2, const float* __restrict__ B2,
    const float* __restrict__ W3, const float* __restrict__ B3,
    float* __restrict__ out, int N)
{
    int n = blockIdx.x * blockDim.x + threadIdx.x;
    if (n >= N) return;
    float xv = x[n];
    float num = 0.f, den = 0.f;
    for (int k = 0; k < KSUB; ++k) {
        float w = window_w(xv, k);
        if (w <= 0.0f) continue;
        float xn = (xv - ((float)k + 0.5f) * 0.0625f) * 10.958904109589041f;
        float o = subnet_eval_g(xn, k, W0, B0, W1, B1, W2, B2, W3, B3);
        num += w * o;
        den += w;
    }
    out[n] = num * __builtin_amdgcn_rcpf(den + 1e-12f);
}

extern "C" void kernel_launch(void* const* d_in, const int* in_sizes, int n_in,
                              void* d_out, int out_size, void* d_ws, size_t ws_size,
                              hipStream_t stream) {
    const float* x  = (const float*)d_in[0];
    const float* W0 = (const float*)d_in[1];
    const float* B0 = (const float*)d_in[2];
    const float* W1 = (const float*)d_in[3];
    const float* B1 = (const float*)d_in[4];
    const float* W2 = (const float*)d_in[5];
    const float* B2 = (const float*)d_in[6];
    const float* W3 = (const float*)d_in[7];
    const float* B3 = (const float*)d_in[8];
    float* out = (float*)d_out;
    const int N = in_sizes[0];

    if ((size_t)TBL * sizeof(float) <= ws_size) {
        float* gnum = (float*)d_ws;
        build_tables<<<TBL / 64, 256, 0, stream>>>(
            W0, B0, W1, B1, W2, B2, W3, B3, gnum);
        int nv = (N + 3) / 4;
        eval_lerp<<<(nv + 255) / 256, 256, 0, stream>>>(x, gnum, out, N);
    } else {
        direct_eval<<<(N + 255) / 256, 256, 0, stream>>>(
            x, W0, B0, W1, B1, W2, B2, W3, B3, out, N);
    }
}

// Round 12
// 19.933 us; speedup vs baseline: 1.4206x; 1.4206x over previous
//
#include <hip/hip_runtime.h>
#include <math.h>

// FBPINN: out(x) = sum_k w_k(x)*subnet_k(x) / sum_k w_k(x), x scalar in [0,1].
// Two dispatches:
//  1) build_tables: numerator table at TBL points, INTERLEAVED by slot:
//     g[i*4+s] = w_{klo(i)+s}(x_i) * o_{klo(i)+s}(x_i). Grid = 512 single-wave
//     blocks (stretch = bx>>2, slot = bx&3; subnet k block-uniform). Weights
//     staged to LDS once (9 coalesced float4 loads), then the MLP reads them
//     with BATCHED ping-pong row buffers: all 9 ds_reads of row o+1 issue
//     while row o's 32 FMAs run -> one waitcnt per row instead of one
//     blocking ~60cyc LDS round-trip per float4. (R8's read->use pattern
//     measured 540 reads x 60cyc = 32K cyc = 13.5us/wave; R9 falsified the
//     throughput model, confirming blocking-latency. This cuts the chain to
//     ~7K cyc ~ 3us.) No atomics, no zero-fill, no __syncthreads.
//  2) eval_lerp: per point two float4 loads fetch the 8 interleaved entries;
//     sum of 4 lerps = lerp of sum; denominator ANALYTIC (<=4 cosine
//     windows of x only). Kernel-boundary coherence (R1-R9 proven).
// Lerp error ~1e-5 at TBL=8192 << 7.3e-3 threshold (bf16 floor 1.95e-3).

#define KSUB 16
#define NW 32
#define TBL 8192
#define NSTRETCH (TBL / 64)   // 128
#define SLOTS 4               // active-k union over a 64-pt stretch <= 4 ints
// LDS layout (floats): W1[1024] W2[1024] W0[32] B0[32] B1[32] B2[32] W3[32]
#define OW1 0
#define OW2 1024
#define OW0 2048
#define OB0 2080
#define OB1 2112
#define OB2 2144
#define OW3 2176
#define LDSF 2208

// tanh(x) = 1 - 2/(exp(2x)+1); v_exp_f32 is exp2 -> scale by 2*log2(e).
static __device__ __forceinline__ float fast_tanh(float v) {
    float e = __builtin_amdgcn_exp2f(v * 2.8853900817779268f);
    return 1.0f - 2.0f * __builtin_amdgcn_rcpf(e + 1.0f);
}

// cos(pi*u), u in [0,1]: v_cos_f32 takes revolutions.
static __device__ __forceinline__ float cos_pi(float u) {
    return __builtin_amdgcn_cosf(0.5f * u);
}

static __device__ __forceinline__ float window_w(float x, int k) {
    const float invTW = 20.0f;  // 1/0.05
    float xmin = (float)k * 0.0625f - 0.06f;
    float xmax = (float)(k + 1) * 0.0625f + 0.06f;
    float up = (x - xmin + 0.025f) * invTW;
    float dn = (xmax + 0.025f - x) * invTW;
    up = fminf(fmaxf(up, 0.0f), 1.0f);
    dn = fminf(fmaxf(dn, 0.0f), 1.0f);
    return 0.25f * (1.0f - cos_pi(up)) * (1.0f - cos_pi(dn));
}

// Active subnets at x: k in (16x-2.36, 16x+1.36) => at most 4, klo..klo+3.
static __device__ __forceinline__ float den_analytic(float xv) {
    int klo = (int)ceilf(16.0f * xv - 2.36f);
    float den = 0.f;
#pragma unroll
    for (int j = 0; j < 4; ++j) {
        int k = klo + j;
        if (k >= 0 && k < KSUB) den += window_w(xv, k);
    }
    return den;
}

// Batched row load: 8 ds_read_b128 + 1 ds_read_b32, one waitcnt group.
#define LOADROW(buf, bvar, wofs, bofs, o)                                   \
    {                                                                       \
        _Pragma("unroll")                                                   \
        for (int q = 0; q < 8; ++q)                                         \
            buf[q] = *reinterpret_cast<const float4*>(&R[(wofs) + (o) * NW + 4 * q]); \
        bvar = R[(bofs) + (o)];                                             \
    }

#define FMAROW(buf, bvar, hin, dst)                                         \
    {                                                                       \
        float a0 = bvar, a1 = 0.f, a2 = 0.f, a3 = 0.f;                      \
        _Pragma("unroll")                                                   \
        for (int q = 0; q < 8; ++q) {                                       \
            a0 = fmaf(buf[q].x, hin[4 * q + 0], a0);                        \
            a1 = fmaf(buf[q].y, hin[4 * q + 1], a1);                        \
            a2 = fmaf(buf[q].z, hin[4 * q + 2], a2);                        \
            a3 = fmaf(buf[q].w, hin[4 * q + 3], a3);                        \
        }                                                                   \
        dst = fast_tanh((a0 + a1) + (a2 + a3));                             \
    }

// grid = NSTRETCH*SLOTS blocks x 64 threads (single wave).
__global__ __launch_bounds__(64) void build_tables(
    const float* __restrict__ W0, const float* __restrict__ B0,
    const float* __restrict__ W1, const float* __restrict__ B1,
    const float* __restrict__ W2, const float* __restrict__ B2,
    const float* __restrict__ W3, const float* __restrict__ B3,
    float* __restrict__ g)
{
    __shared__ float R[LDSF];   // 8.6 KB weight region

    const int lane = threadIdx.x;         // 0..63
    const int str  = blockIdx.x >> 2;
    const int slot = blockIdx.x & 3;
    const int i    = str * 64 + lane;
    const float inv = 1.0f / (float)(TBL - 1);
    const float xg  = (float)i * inv;

    float x_lo = (float)(str * 64) * inv;
    int klo_b = (int)ceilf(16.0f * x_lo - 2.36f);
    const int k  = klo_b + slot;          // block-uniform
    const int kc = min(max(k, 0), KSUB - 1);

    // ---- stage this subnet's weights into LDS (one memory round-trip) ----
    {
        const float4* gW1 = reinterpret_cast<const float4*>(&W1[kc * NW * NW]);
        const float4* gW2 = reinterpret_cast<const float4*>(&W2[kc * NW * NW]);
        float4 t0 = gW1[0 * 64 + lane];
        float4 t1 = gW1[1 * 64 + lane];
        float4 t2 = gW1[2 * 64 + lane];
        float4 t3 = gW1[3 * 64 + lane];
        float4 t4 = gW2[0 * 64 + lane];
        float4 t5 = gW2[1 * 64 + lane];
        float4 t6 = gW2[2 * 64 + lane];
        float4 t7 = gW2[3 * 64 + lane];
        float4 t8;
        const int a = lane >> 3;          // 0..7 (0..4 carry data)
        const int e = (lane & 7) * 4;
        const float* sp = (a == 0) ? &W0[kc * NW] :
                          (a == 1) ? &B0[kc * NW] :
                          (a == 2) ? &B1[kc * NW] :
                          (a == 3) ? &B2[kc * NW] : &W3[kc * NW];
        if (a < 5) t8 = *reinterpret_cast<const float4*>(&sp[e]);
        *reinterpret_cast<float4*>(&R[OW1 + 0 * 256 + lane * 4]) = t0;
        *reinterpret_cast<float4*>(&R[OW1 + 1 * 256 + lane * 4]) = t1;
        *reinterpret_cast<float4*>(&R[OW1 + 2 * 256 + lane * 4]) = t2;
        *reinterpret_cast<float4*>(&R[OW1 + 3 * 256 + lane * 4]) = t3;
        *reinterpret_cast<float4*>(&R[OW2 + 0 * 256 + lane * 4]) = t4;
        *reinterpret_cast<float4*>(&R[OW2 + 1 * 256 + lane * 4]) = t5;
        *reinterpret_cast<float4*>(&R[OW2 + 2 * 256 + lane * 4]) = t6;
        *reinterpret_cast<float4*>(&R[OW2 + 3 * 256 + lane * 4]) = t7;
        if (a < 5)
            *reinterpret_cast<float4*>(&R[OW0 + a * 32 + e]) = t8;
    }
    // same-wave ds_write -> ds_read ordering handled by lgkmcnt (R8-proven).

    // ---- evaluate subnet kc at this lane's point ----
    const float INVS = 10.958904109589041f;  // 1/0.09125 (uniform scale)
    float xn = (xg - ((float)kc + 0.5f) * 0.0625f) * INVS;

    float h0[NW], h1[NW];
    // layer 0: one batched group (16 reads, one waitcnt)
    {
        float4 wv[8], bv[8];
#pragma unroll
        for (int q = 0; q < 8; ++q)
            wv[q] = *reinterpret_cast<const float4*>(&R[OW0 + 4 * q]);
#pragma unroll
        for (int q = 0; q < 8; ++q)
            bv[q] = *reinterpret_cast<const float4*>(&R[OB0 + 4 * q]);
#pragma unroll
        for (int q = 0; q < 8; ++q) {
            h0[4 * q + 0] = fast_tanh(fmaf(wv[q].x, xn, bv[q].x));
            h0[4 * q + 1] = fast_tanh(fmaf(wv[q].y, xn, bv[q].y));
            h0[4 * q + 2] = fast_tanh(fmaf(wv[q].z, xn, bv[q].z));
            h0[4 * q + 3] = fast_tanh(fmaf(wv[q].w, xn, bv[q].w));
        }
    }
    // layers 1 & 2: ping-pong row buffers (next row's reads hide under FMAs)
    {
        float4 bufA[8], bufB[8];
        float bA, bB;
        LOADROW(bufA, bA, OW1, OB1, 0);
#pragma unroll
        for (int o = 0; o < NW; o += 2) {
            LOADROW(bufB, bB, OW1, OB1, o + 1);
            FMAROW(bufA, bA, h0, h1[o]);
            if (o + 2 < NW) LOADROW(bufA, bA, OW1, OB1, o + 2);
            FMAROW(bufB, bB, h0, h1[o + 1]);
        }
        LOADROW(bufA, bA, OW2, OB2, 0);
#pragma unroll
        for (int o = 0; o < NW; o += 2) {
            LOADROW(bufB, bB, OW2, OB2, o + 1);
            FMAROW(bufA, bA, h1, h0[o]);          // h0 reused as h2
            if (o + 2 < NW) LOADROW(bufA, bA, OW2, OB2, o + 2);
            FMAROW(bufB, bB, h1, h0[o + 1]);
        }
    }
    // layer 3: batched
    float out_o;
    {
        float4 wv[8];
#pragma unroll
        for (int q = 0; q < 8; ++q)
            wv[q] = *reinterpret_cast<const float4*>(&R[OW3 + 4 * q]);
        float a0 = B3[kc], a1 = 0.f, a2 = 0.f, a3 = 0.f;
#pragma unroll
        for (int q = 0; q < 8; ++q) {
            a0 = fmaf(wv[q].x, h0[4 * q + 0], a0);
            a1 = fmaf(wv[q].y, h0[4 * q + 1], a1);
            a2 = fmaf(wv[q].z, h0[4 * q + 2], a2);
            a3 = fmaf(wv[q].w, h0[4 * q + 3], a3);
        }
        out_o = (a0 + a1) + (a2 + a3);
    }

    float wgt = window_w(xg, kc);
    g[i * 4 + slot] = (k >= 0 && k < KSUB) ? wgt * out_o : 0.0f;
}

static __device__ __forceinline__ float eval_point(
    float xj, const float* __restrict__ g)
{
    const float scaleT = (float)(TBL - 1);
    float t = fminf(fmaxf(xj * scaleT, 0.0f), scaleT);
    int i0 = (int)t;
    if (i0 > TBL - 2) i0 = TBL - 2;
    float f = t - (float)i0;
    float4 a = *reinterpret_cast<const float4*>(&g[i0 * 4]);
    float4 b = *reinterpret_cast<const float4*>(&g[i0 * 4 + 4]);
    float n0 = (a.x + a.y) + (a.z + a.w);
    float n1 = (b.x + b.y) + (b.z + b.w);
    float num = fmaf(f, n1 - n0, n0);
    float den = den_analytic(xj);
    return num * __builtin_amdgcn_rcpf(den + 1e-12f);
}

// float4 lerp pass over the N points.
__global__ void eval_lerp(const float* __restrict__ x,
                          const float* __restrict__ g,
                          float* __restrict__ out, int N)
{
    int idx = blockIdx.x * blockDim.x + threadIdx.x;
    int base = idx * 4;
    if (base + 3 < N) {
        float4 xv = *reinterpret_cast<const float4*>(&x[base]);
        float4 r;
        r.x = eval_point(xv.x, g);
        r.y = eval_point(xv.y, g);
        r.z = eval_point(xv.z, g);
        r.w = eval_point(xv.w, g);
        *reinterpret_cast<float4*>(&out[base]) = r;
    } else {
        for (int j = base; j < N; ++j) out[j] = eval_point(x[j], g);
    }
}

// ---- fallback path (tiny ws only): direct evaluation via global loads ----
static __device__ __forceinline__ float subnet_eval_g(
    float xn, int kc,
    const float* __restrict__ W0, const float* __restrict__ B0,
    const float* __restrict__ W1, const float* __restrict__ B1,
    const float* __restrict__ W2, const float* __restrict__ B2,
    const float* __restrict__ W3, const float* __restrict__ B3)
{
    float h0[NW], h1[NW];
#pragma unroll
    for (int o = 0; o < NW; ++o)
        h0[o] = fast_tanh(fmaf(W0[kc * NW + o], xn, B0[kc * NW + o]));
#pragma unroll
    for (int o = 0; o < NW; ++o) {
        float a = B1[kc * NW + o];
        const float* row = &W1[kc * NW * NW + o * NW];
#pragma unroll
        for (int j = 0; j < NW; ++j) a = fmaf(row[j], h0[j], a);
        h1[o] = fast_tanh(a);
    }
#pragma unroll
    for (int o = 0; o < NW; ++o) {
        float a = B2[kc * NW + o];
        const float* row = &W2[kc * NW * NW + o * NW];
#pragma unroll
        for (int j = 0; j < NW; ++j) a = fmaf(row[j], h1[j], a);
        h0[o] = fast_tanh(a);
    }
    float a = B3[kc];
#pragma unroll
    for (int j = 0; j < NW; ++j) a = fmaf(W3[kc * NW + j], h0[j], a);
    return a;
}

__global__ void direct_eval(
    const float* __restrict__ x,
    const float* __restrict__ W0, const float* __restrict__ B0,
    const float* __restrict__ W1, const float* __restrict__ B1,
    const float* __restrict__ W2, const float* __restrict__ B2,
    const float* __restrict__ W3, const float* __restrict__ B3,
    float* __restrict__ out, int N)
{
    int n = blockIdx.x * blockDim.x + threadIdx.x;
    if (n >= N) return;
    float xv = x[n];
    float num = 0.f, den = 0.f;
    for (int k = 0; k < KSUB; ++k) {
        float w = window_w(xv, k);
        if (w <= 0.0f) continue;
        float xn = (xv - ((float)k + 0.5f) * 0.0625f) * 10.958904109589041f;
        float o = subnet_eval_g(xn, k, W0, B0, W1, B1, W2, B2, W3, B3);
        num += w * o;
        den += w;
    }
    out[n] = num * __builtin_amdgcn_rcpf(den + 1e-12f);
}

extern "C" void kernel_launch(void* const* d_in, const int* in_sizes, int n_in,
                              void* d_out, int out_size, void* d_ws, size_t ws_size,
                              hipStream_t stream) {
    const float* x  = (const float*)d_in[0];
    const float* W0 = (const float*)d_in[1];
    const float* B0 = (const float*)d_in[2];
    const float* W1 = (const float*)d_in[3];
    const float* B1 = (const float*)d_in[4];
    const float* W2 = (const float*)d_in[5];
    const float* B2 = (const float*)d_in[6];
    const float* W3 = (const float*)d_in[7];
    const float* B3 = (const float*)d_in[8];
    float* out = (float*)d_out;
    const int N = in_sizes[0];

    if ((size_t)TBL * 4 * sizeof(float) <= ws_size) {
        float* g = (float*)d_ws;
        build_tables<<<NSTRETCH * SLOTS, 64, 0, stream>>>(
            W0, B0, W1, B1, W2, B2, W3, B3, g);
        int nv = (N + 3) / 4;
        eval_lerp<<<(nv + 255) / 256, 256, 0, stream>>>(x, g, out, N);
    } else {
        direct_eval<<<(N + 255) / 256, 256, 0, stream>>>(
            x, W0, B0, W1, B1, W2, B2, W3, B3, out, N);
    }
}